// Round 5
// baseline (417.821 us; speedup 1.0000x reference)
//
#include <hip/hip_runtime.h>
#include <hip/hip_bf16.h>
#include <stdint.h>

// MFMA fragment types (gfx950: mfma_f32_16x16x32_bf16 takes <8 x bf16>)
typedef __bf16 bf16x8 __attribute__((ext_vector_type(8)));
typedef float  f32x4  __attribute__((ext_vector_type(4)));

#define MFMA(A, B, C) __builtin_amdgcn_mfma_f32_16x16x32_bf16((A), (B), (C), 0, 0, 0)

// Raw workgroup barrier: waits LDS ops only, leaves global loads in flight
// (the compiler's __syncthreads() emits s_waitcnt vmcnt(0) which would drain
// our gather prefetch every k-iteration — that is the structural stall).
#define LDS_BARRIER() asm volatile("s_waitcnt lgkmcnt(0)\n\ts_barrier" ::: "memory")

// fp32 -> bf16 round-to-nearest-even
static __device__ __forceinline__ unsigned short f2b(float f) {
    union { float f; unsigned int u; } v; v.f = f;
    return (unsigned short)((v.u + 0x7FFFu + ((v.u >> 16) & 1u)) >> 16);
}

// ---------------------------------------------------------------------------
// Kernel 1: x fp32 -> bf16 [N+1][128]; zero pad row N of x_bf16 and h_comb.
// ---------------------------------------------------------------------------
__global__ __launch_bounds__(256) void convert_kernel(
    const float* __restrict__ x, unsigned short* __restrict__ xb,
    unsigned short* __restrict__ hb, int N) {
    long long i = (long long)blockIdx.x * blockDim.x + threadIdx.x; // 4 elems each
    long long base = i * 4;
    long long nx = (long long)N * 128;
    long long total = nx + 128;
    if (base >= total) return;
    if (base < nx) {
        float4 v = *(const float4*)(x + base);
        ushort4 o;
        o.x = f2b(v.x); o.y = f2b(v.y); o.z = f2b(v.z); o.w = f2b(v.w);
        *(ushort4*)(xb + base) = o;
    } else {
        ushort4 z = make_ushort4(0, 0, 0, 0);
        *(ushort4*)(xb + base) = z;   // pad row (index == N -> zeros)
        *(ushort4*)(hb + base) = z;
    }
}

// ---------------------------------------------------------------------------
// Kernel 2: pack weights into MFMA B-fragment order.
// wp00: per-k contiguous 16KB slices (k*8192 + (s*4+t)*512 + lane*8); the
//       first 4096 shorts of each slice are cin 0-63 (phase 0), second half
//       cin 64-127 (phase 1).
// wpC : conv01 and conv11 k-slices interleaved: k*8192 + [0|4096] + ...
// ---------------------------------------------------------------------------
__global__ __launch_bounds__(256) void pack_kernel(
    const float* __restrict__ W00, const float* __restrict__ W01,
    const float* __restrict__ W10, const float* __restrict__ W11,
    const float* __restrict__ W12,
    unsigned short* __restrict__ wp00, unsigned short* __restrict__ wpC,
    unsigned short* __restrict__ wp10, unsigned short* __restrict__ wp12) {
    int g = blockIdx.x * blockDim.x + threadIdx.x;
    const float* W; int cinSteps; int which;
    if (g < 27648)      { W = W00; cinSteps = 4; which = 0; }
    else if (g < 41472) { g -= 27648; W = W01; cinSteps = 2; which = 1; }
    else if (g < 55296) { g -= 41472; W = W11; cinSteps = 2; which = 2; }
    else if (g < 56320) { g -= 55296; W = W10; cinSteps = 4; which = 3; }
    else if (g < 56832) { g -= 56320; W = W12; cinSteps = 2; which = 4; }
    else return;
    int lane = g & 63;
    int st   = g >> 6;
    int t    = st & 3;
    int s    = st >> 2;
    int q = lane >> 4, n16 = lane & 15;
    int k    = s / cinSteps;
    int cinb = (s % cinSteps) * 32;
    int Cin  = cinSteps * 32;
    int cout = t * 16 + n16;
    unsigned short o[8];
#pragma unroll
    for (int j = 0; j < 8; ++j) {
        float v = W[(size_t)(k * Cin + cinb + q * 8 + j) * 64 + cout];
        o[j] = f2b(v);
    }
    unsigned short* dst;
    if (which == 0)      dst = wp00 + (size_t)g * 8;
    else if (which == 1) dst = wpC + (size_t)k * 8192 +
                               ((size_t)(((s & 1) * 4 + t) * 64 + lane)) * 8;
    else if (which == 2) dst = wpC + (size_t)k * 8192 + 4096 +
                               ((size_t)(((s & 1) * 4 + t) * 64 + lane)) * 8;
    else if (which == 3) dst = wp10 + (size_t)g * 8;
    else                 dst = wp12 + (size_t)g * 8;
    *(ushort4*)(dst)     = make_ushort4(o[0], o[1], o[2], o[3]);
    *(ushort4*)(dst + 4) = make_ushort4(o[4], o[5], o[6], o[7]);
}

// ---------------------------------------------------------------------------
// Pass B: h0 = relu(sparse_conv(x, W00, b00)); h1 = relu(x @ W10 + b10)
// One block per 128-row strip; 32 rows/wave.  CHANNEL-SPLIT PHASES: phase 0
// gathers only cin 0-63 (128B of each row), phase 1 cin 64-127.  Per-phase
// gather working set = 12.8 MB (vs 25.6) -> better per-XCD L2 hit rate at
// identical total bytes and 128B-transaction count.  Accumulators persist in
// registers across phases.  Gathers are 2-deep prefetched (Da/Db/Dc) in MFMA
// A-layout; B half-tiles (8KB) staged in LDS double-buffered with LDS-only
// barriers so gathers stay in flight.
// ---------------------------------------------------------------------------
__global__ __launch_bounds__(256, 3) void passB_kernel(
    const unsigned short* __restrict__ xb, const int* __restrict__ nbr,
    const unsigned short* __restrict__ wp00, const unsigned short* __restrict__ wp10,
    const float* __restrict__ b00, const float* __restrict__ b10,
    unsigned short* __restrict__ hb, int N) {
    __shared__ __align__(16) unsigned short bbuf[2][4096];
    __shared__ __align__(16) int lds_idx[128 * 27];
    const int tid  = threadIdx.x;
    const int lane = tid & 63;
    const int wv   = tid >> 6;
    const int q = lane >> 4, n16 = lane & 15;
    const int rowbase = blockIdx.x * 128 + wv * 32;

    f32x4 acc0[2][4];   // conv0_0 accum [rowset][t] — spans both phases
    f32x4 acc1[2][4];   // conv1_0 (1x1) accum — spans both phases
#pragma unroll
    for (int rs = 0; rs < 2; ++rs)
#pragma unroll
        for (int t = 0; t < 4; ++t) { acc0[rs][t] = (f32x4)0.f; acc1[rs][t] = (f32x4)0.f; }

    int idxb[2], own[2];
#pragma unroll
    for (int rs = 0; rs < 2; ++rs) {
        idxb[rs] = (wv * 32 + rs * 16 + n16) * 27;      // this lane's A-row
        own[rs]  = min(rowbase + rs * 16 + n16, N - 1); // own rows (clamped)
    }

#pragma unroll
    for (int ph = 0; ph < 2; ++ph) {
        const int choff = ph * 64;   // channel offset in shorts
        // stage B(0) half-tile for this phase
        int4 br[2];
#pragma unroll
        for (int j = 0; j < 2; ++j)
            br[j] = *(const int4*)(wp00 + ph * 4096 + j * 2048 + tid * 8);
        if (ph == 0) {  // stage the strip's nbr slice once
            long long gbase = (long long)blockIdx.x * 128 * 27;
            long long lim = (long long)N * 27 - 1;
            for (int i = tid; i < 3456; i += 256) {
                long long gi = gbase + i; if (gi > lim) gi = lim;
                lds_idx[i] = nbr[gi];
            }
        }
#pragma unroll
        for (int j = 0; j < 2; ++j) *(int4*)(&bbuf[0][j * 2048 + tid * 8]) = br[j];
        __syncthreads();   // phase boundary: full drain (2x per kernel, cheap)

        // 2-deep gather prologue: Da=g(0), Db=g(1)  (MFMA A-layout directly)
        bf16x8 Da[2][2], Db[2][2], Dc[2][2];
#pragma unroll
        for (int rs = 0; rs < 2; ++rs) {
            const unsigned short* p0 =
                xb + (size_t)lds_idx[idxb[rs] + 0] * 128 + choff + q * 8;
            Da[rs][0] = *(const bf16x8*)(p0);
            Da[rs][1] = *(const bf16x8*)(p0 + 32);
            const unsigned short* p1 =
                xb + (size_t)lds_idx[idxb[rs] + 1] * 128 + choff + q * 8;
            Db[rs][0] = *(const bf16x8*)(p1);
            Db[rs][1] = *(const bf16x8*)(p1 + 32);
        }

        for (int k = 0; k < 27; ++k) {
            int buf = k & 1;
            if (k < 26) {   // B(k+1) half-tile -> regs (issued before gathers)
                const unsigned short* src = wp00 + ph * 4096 + (size_t)(k + 1) * 8192;
#pragma unroll
                for (int j = 0; j < 2; ++j)
                    br[j] = *(const int4*)(src + j * 2048 + tid * 8);
            }
            // issue gather g(k+2); past end -> own row (feeds the 1x1)
#pragma unroll
            for (int rs = 0; rs < 2; ++rs) {
                int j2 = k + 2;
                int ii = (j2 < 27) ? lds_idx[idxb[rs] + j2] : own[rs];
                const unsigned short* p = xb + (size_t)ii * 128 + choff + q * 8;
                Dc[rs][0] = *(const bf16x8*)(p);
                Dc[rs][1] = *(const bf16x8*)(p + 32);
            }
            // MFMA with LDS B(k); Da already in MFMA layout
            const unsigned short* lb = &bbuf[buf][0];
#pragma unroll
            for (int s2 = 0; s2 < 2; ++s2) {
#pragma unroll
                for (int t = 0; t < 4; ++t) {
                    bf16x8 B = *(const bf16x8*)(lb + (s2 * 4 + t) * 512 + lane * 8);
#pragma unroll
                    for (int rs = 0; rs < 2; ++rs)
                        acc0[rs][t] = MFMA(Da[rs][s2], B, acc0[rs][t]);
                }
            }
            if (k < 26) {   // vmcnt here drains only br (+older Db, on time)
#pragma unroll
                for (int j = 0; j < 2; ++j)
                    *(int4*)(&bbuf[buf ^ 1][j * 2048 + tid * 8]) = br[j];
            }
#pragma unroll
            for (int rs = 0; rs < 2; ++rs)
#pragma unroll
                for (int s2 = 0; s2 < 2; ++s2) {
                    Da[rs][s2] = Db[rs][s2]; Db[rs][s2] = Dc[rs][s2];
                }
            LDS_BARRIER();   // LDS-only drain: gathers stay in flight
        }

        // fused 1x1 conv, this phase's cin half: Da = own rows
#pragma unroll
        for (int s2 = 0; s2 < 2; ++s2) {
#pragma unroll
            for (int t = 0; t < 4; ++t) {
                bf16x8 B = *(const bf16x8*)(wp10 + ((ph * 2 + s2) * 4 + t) * 512 + lane * 8);
#pragma unroll
                for (int rs = 0; rs < 2; ++rs)
                    acc1[rs][t] = MFMA(Da[rs][s2], B, acc1[rs][t]);
            }
        }
    }

    // epilogue: bias, relu, -> bf16, store h_comb.  C-layout: col=lane&15
#pragma unroll
    for (int rs = 0; rs < 2; ++rs)
#pragma unroll
        for (int t = 0; t < 4; ++t) {
            int col = t * 16 + n16;
            float bb0 = b00[col], bb1 = b10[col];
#pragma unroll
            for (int r = 0; r < 4; ++r) {
                int row = rowbase + rs * 16 + q * 4 + r;
                if (row < N) {
                    hb[(size_t)row * 128 + col]      = f2b(fmaxf(acc0[rs][t][r] + bb0, 0.f));
                    hb[(size_t)row * 128 + 64 + col] = f2b(fmaxf(acc1[rs][t][r] + bb1, 0.f));
                }
            }
        }
}

// ---------------------------------------------------------------------------
// Pass C: out0 = sparse_conv(h0, W01, b01);  t = relu(sparse_conv(h1, W11, b11));
//         out1 = t @ W12 + b12;  out = [out0 | out1] + x  (fp32)
// The two convs ARE the channel split: phase 1 gathers only h0 (bytes 0-127),
// phase 2 only h1 (bytes 128-255).  out0 is stored at end of phase 1, freeing
// its accumulator before phase 2.
// ---------------------------------------------------------------------------
__global__ __launch_bounds__(256, 3) void passC_kernel(
    const unsigned short* __restrict__ hb, const int* __restrict__ nbr,
    const float* __restrict__ x,
    const unsigned short* __restrict__ wpC, const unsigned short* __restrict__ wp12,
    const float* __restrict__ b01, const float* __restrict__ b11,
    const float* __restrict__ b12, float* __restrict__ out, int N) {
    __shared__ __align__(16) unsigned short bbuf[2][4096];
    __shared__ __align__(16) int lds_idx[128 * 27];
    const int tid  = threadIdx.x;
    const int lane = tid & 63;
    const int wv   = tid >> 6;
    const int q = lane >> 4, n16 = lane & 15;
    const int rowbase = blockIdx.x * 128 + wv * 32;

    int idxb[2];
#pragma unroll
    for (int rs = 0; rs < 2; ++rs) idxb[rs] = (wv * 32 + rs * 16 + n16) * 27;

    // ================= phase 1: conv01 on h0-half =================
    {
        int4 br[2];
#pragma unroll
        for (int j = 0; j < 2; ++j) br[j] = *(const int4*)(wpC + j * 2048 + tid * 8);
        {
            long long gbase = (long long)blockIdx.x * 128 * 27;
            long long lim = (long long)N * 27 - 1;
            for (int i = tid; i < 3456; i += 256) {
                long long gi = gbase + i; if (gi > lim) gi = lim;
                lds_idx[i] = nbr[gi];
            }
        }
#pragma unroll
        for (int j = 0; j < 2; ++j) *(int4*)(&bbuf[0][j * 2048 + tid * 8]) = br[j];
        __syncthreads();

        f32x4 accA[2][4];
#pragma unroll
        for (int rs = 0; rs < 2; ++rs)
#pragma unroll
            for (int t = 0; t < 4; ++t) accA[rs][t] = (f32x4)0.f;

        bf16x8 Da[2][2], Db[2][2], Dc[2][2];
#pragma unroll
        for (int rs = 0; rs < 2; ++rs) {
            const unsigned short* p0 = hb + (size_t)lds_idx[idxb[rs] + 0] * 128 + q * 8;
            Da[rs][0] = *(const bf16x8*)(p0);
            Da[rs][1] = *(const bf16x8*)(p0 + 32);
            const unsigned short* p1 = hb + (size_t)lds_idx[idxb[rs] + 1] * 128 + q * 8;
            Db[rs][0] = *(const bf16x8*)(p1);
            Db[rs][1] = *(const bf16x8*)(p1 + 32);
        }

        for (int k = 0; k < 27; ++k) {
            int buf = k & 1;
            if (k < 26) {
                const unsigned short* src = wpC + (size_t)(k + 1) * 8192;
#pragma unroll
                for (int j = 0; j < 2; ++j)
                    br[j] = *(const int4*)(src + j * 2048 + tid * 8);
            }
#pragma unroll
            for (int rs = 0; rs < 2; ++rs) {
                int j2 = min(k + 2, 26);   // clamp: harmless re-gather at tail
                const unsigned short* p =
                    hb + (size_t)lds_idx[idxb[rs] + j2] * 128 + q * 8;
                Dc[rs][0] = *(const bf16x8*)(p);
                Dc[rs][1] = *(const bf16x8*)(p + 32);
            }
            const unsigned short* lb = &bbuf[buf][0];
#pragma unroll
            for (int s2 = 0; s2 < 2; ++s2) {
#pragma unroll
                for (int t = 0; t < 4; ++t) {
                    bf16x8 B = *(const bf16x8*)(lb + (s2 * 4 + t) * 512 + lane * 8);
#pragma unroll
                    for (int rs = 0; rs < 2; ++rs)
                        accA[rs][t] = MFMA(Da[rs][s2], B, accA[rs][t]);
                }
            }
            if (k < 26) {
#pragma unroll
                for (int j = 0; j < 2; ++j)
                    *(int4*)(&bbuf[buf ^ 1][j * 2048 + tid * 8]) = br[j];
            }
#pragma unroll
            for (int rs = 0; rs < 2; ++rs)
#pragma unroll
                for (int s2 = 0; s2 < 2; ++s2) {
                    Da[rs][s2] = Db[rs][s2]; Db[rs][s2] = Dc[rs][s2];
                }
            LDS_BARRIER();
        }

        // epilogue 1: out0 = accA + b01 + x  (frees accA before phase 2)
#pragma unroll
        for (int rs = 0; rs < 2; ++rs)
#pragma unroll
            for (int t = 0; t < 4; ++t) {
                int col = t * 16 + n16;
                float bo = b01[col];
#pragma unroll
                for (int r = 0; r < 4; ++r) {
                    int row = rowbase + rs * 16 + q * 4 + r;
                    if (row < N) {
                        float xv = __builtin_nontemporal_load(x + (size_t)row * 128 + col);
                        __builtin_nontemporal_store(accA[rs][t][r] + bo + xv,
                                                    out + (size_t)row * 128 + col);
                    }
                }
            }
    }

    // ================= phase 2: conv11 on h1-half =================
    {
        int4 br[2];
#pragma unroll
        for (int j = 0; j < 2; ++j)
            br[j] = *(const int4*)(wpC + 4096 + j * 2048 + tid * 8);
#pragma unroll
        for (int j = 0; j < 2; ++j) *(int4*)(&bbuf[0][j * 2048 + tid * 8]) = br[j];
        __syncthreads();

        f32x4 accT[2][4];
#pragma unroll
        for (int rs = 0; rs < 2; ++rs)
#pragma unroll
            for (int t = 0; t < 4; ++t) accT[rs][t] = (f32x4)0.f;

        bf16x8 Da[2][2], Db[2][2], Dc[2][2];
#pragma unroll
        for (int rs = 0; rs < 2; ++rs) {
            const unsigned short* p0 =
                hb + (size_t)lds_idx[idxb[rs] + 0] * 128 + 64 + q * 8;
            Da[rs][0] = *(const bf16x8*)(p0);
            Da[rs][1] = *(const bf16x8*)(p0 + 32);
            const unsigned short* p1 =
                hb + (size_t)lds_idx[idxb[rs] + 1] * 128 + 64 + q * 8;
            Db[rs][0] = *(const bf16x8*)(p1);
            Db[rs][1] = *(const bf16x8*)(p1 + 32);
        }

        for (int k = 0; k < 27; ++k) {
            int buf = k & 1;
            if (k < 26) {
                const unsigned short* src = wpC + 4096 + (size_t)(k + 1) * 8192;
#pragma unroll
                for (int j = 0; j < 2; ++j)
                    br[j] = *(const int4*)(src + j * 2048 + tid * 8);
            }
#pragma unroll
            for (int rs = 0; rs < 2; ++rs) {
                int j2 = min(k + 2, 26);
                const unsigned short* p =
                    hb + (size_t)lds_idx[idxb[rs] + j2] * 128 + 64 + q * 8;
                Dc[rs][0] = *(const bf16x8*)(p);
                Dc[rs][1] = *(const bf16x8*)(p + 32);
            }
            const unsigned short* lb = &bbuf[buf][0];
#pragma unroll
            for (int s2 = 0; s2 < 2; ++s2) {
#pragma unroll
                for (int t = 0; t < 4; ++t) {
                    bf16x8 B = *(const bf16x8*)(lb + (s2 * 4 + t) * 512 + lane * 8);
#pragma unroll
                    for (int rs = 0; rs < 2; ++rs)
                        accT[rs][t] = MFMA(Da[rs][s2], B, accT[rs][t]);
                }
            }
            if (k < 26) {
#pragma unroll
                for (int j = 0; j < 2; ++j)
                    *(int4*)(&bbuf[buf ^ 1][j * 2048 + tid * 8]) = br[j];
            }
#pragma unroll
            for (int rs = 0; rs < 2; ++rs)
#pragma unroll
                for (int s2 = 0; s2 < 2; ++s2) {
                    Da[rs][s2] = Db[rs][s2]; Db[rs][s2] = Dc[rs][s2];
                }
            LDS_BARRIER();   // final one also fences lds_idx/bbuf for overlay
        }

        // t -> relu -> bf16 -> LDS scratch (per-wave private region).
        // Overlay: waves 0-2 use lds_idx (3 x 4608B = 13824B exactly),
        // wave 3 uses bbuf.  All idx/bbuf reads completed before the final
        // LDS_BARRIER above.
        unsigned short* myl = (wv < 3) ? ((unsigned short*)lds_idx + wv * 2304)
                                       : &bbuf[0][0];
#pragma unroll
        for (int rs = 0; rs < 2; ++rs)
#pragma unroll
            for (int t = 0; t < 4; ++t) {
                int col = t * 16 + n16;
                float bt = b11[col];
#pragma unroll
                for (int r = 0; r < 4; ++r) {
                    float tv = fmaxf(accT[rs][t][r] + bt, 0.f);
                    myl[(rs * 16 + q * 4 + r) * 72 + col] = f2b(tv);
                }
            }
        // per-wave private region: within-wave lgkm ordering suffices

        // mini-GEMM: out1 = relu(t) @ W12
        f32x4 accO1[2][4];
#pragma unroll
        for (int rs = 0; rs < 2; ++rs)
#pragma unroll
            for (int t = 0; t < 4; ++t) accO1[rs][t] = (f32x4)0.f;
#pragma unroll
        for (int s2 = 0; s2 < 2; ++s2) {
#pragma unroll
            for (int t = 0; t < 4; ++t) {
                bf16x8 B = *(const bf16x8*)(wp12 + s2 * 2048 + t * 512 + lane * 8);
#pragma unroll
                for (int rs = 0; rs < 2; ++rs) {
                    bf16x8 A = *(const bf16x8*)(myl + (rs * 16 + n16) * 72 + s2 * 32 + q * 8);
                    accO1[rs][t] = MFMA(A, B, accO1[rs][t]);
                }
            }
        }
#pragma unroll
        for (int rs = 0; rs < 2; ++rs)
#pragma unroll
            for (int t = 0; t < 4; ++t) {
                int col = t * 16 + n16;
                float bo = b12[col];
#pragma unroll
                for (int r = 0; r < 4; ++r) {
                    int row = rowbase + rs * 16 + q * 4 + r;
                    if (row < N) {
                        float xv = __builtin_nontemporal_load(x + (size_t)row * 128 + 64 + col);
                        __builtin_nontemporal_store(accO1[rs][t][r] + bo + xv,
                                                    out + (size_t)row * 128 + 64 + col);
                    }
                }
            }
    }
}

// ---------------------------------------------------------------------------
extern "C" void kernel_launch(void* const* d_in, const int* in_sizes, int n_in,
                              void* d_out, int out_size, void* d_ws, size_t ws_size,
                              hipStream_t stream) {
    const float* x   = (const float*)d_in[0];
    const int*   nbr = (const int*)d_in[1];
    const float* W00 = (const float*)d_in[2];
    const float* b00 = (const float*)d_in[3];
    const float* W01 = (const float*)d_in[4];
    const float* b01 = (const float*)d_in[5];
    const float* W10 = (const float*)d_in[6];
    const float* b10 = (const float*)d_in[7];
    const float* W11 = (const float*)d_in[8];
    const float* b11 = (const float*)d_in[9];
    const float* W12 = (const float*)d_in[10];
    const float* b12 = (const float*)d_in[11];
    float* out = (float*)d_out;
    int N = in_sizes[0] / 128;   // 100000

    // workspace carve-up
    char* ws = (char*)d_ws;
    size_t cur = 0;
    unsigned short* xb  = (unsigned short*)(ws + cur); cur += (size_t)(N + 1) * 128 * 2;
    unsigned short* hb  = (unsigned short*)(ws + cur); cur += (size_t)(N + 1) * 128 * 2;
    unsigned short* wp00 = (unsigned short*)(ws + cur); cur += 27648 * 8 * 2;
    unsigned short* wpC  = (unsigned short*)(ws + cur); cur += (size_t)27 * 8192 * 2;
    unsigned short* wp10 = (unsigned short*)(ws + cur); cur += 8192 * 2;
    unsigned short* wp12 = (unsigned short*)(ws + cur); cur += 4096 * 2;

    long long cvt_groups = ((long long)N * 128 + 128) / 4;
    int cvt_blocks = (int)((cvt_groups + 255) / 256);
    convert_kernel<<<cvt_blocks, 256, 0, stream>>>(x, xb, hb, N);
    pack_kernel<<<222, 256, 0, stream>>>(W00, W01, W10, W11, W12,
                                         wp00, wpC, wp10, wp12);
    int nstrips = (N + 127) / 128;   // 782 strips of 128 rows, 1 block each
    passB_kernel<<<nstrips, 256, 0, stream>>>(xb, nbr, wp00, wp10, b00, b10, hb, N);
    passC_kernel<<<nstrips, 256, 0, stream>>>(hb, nbr, x, wpC, wp12,
                                              b01, b11, b12, out, N);
}

// Round 6
// 393.099 us; speedup vs baseline: 1.0629x; 1.0629x over previous
//
#include <hip/hip_runtime.h>
#include <hip/hip_bf16.h>
#include <stdint.h>

// MFMA fragment types (gfx950: mfma_f32_16x16x32_bf16 takes <8 x bf16>)
typedef __bf16 bf16x8 __attribute__((ext_vector_type(8)));
typedef float  f32x4  __attribute__((ext_vector_type(4)));

#define MFMA(A, B, C) __builtin_amdgcn_mfma_f32_16x16x32_bf16((A), (B), (C), 0, 0, 0)

// Raw workgroup barrier: waits LDS ops only, leaves global loads in flight
// (the compiler's __syncthreads() emits s_waitcnt vmcnt(0) which would drain
// our gather prefetch every k-iteration — that is the structural stall).
#define LDS_BARRIER() asm volatile("s_waitcnt lgkmcnt(0)\n\ts_barrier" ::: "memory")

// fp32 -> bf16 round-to-nearest-even
static __device__ __forceinline__ unsigned short f2b(float f) {
    union { float f; unsigned int u; } v; v.f = f;
    return (unsigned short)((v.u + 0x7FFFu + ((v.u >> 16) & 1u)) >> 16);
}

// ---------------------------------------------------------------------------
// Kernel 1: x fp32 -> bf16 [N+1][128]; zero pad row N of x_bf16 and h_comb.
// ---------------------------------------------------------------------------
__global__ __launch_bounds__(256) void convert_kernel(
    const float* __restrict__ x, unsigned short* __restrict__ xb,
    unsigned short* __restrict__ hb, int N) {
    long long i = (long long)blockIdx.x * blockDim.x + threadIdx.x; // 4 elems each
    long long base = i * 4;
    long long nx = (long long)N * 128;
    long long total = nx + 128;
    if (base >= total) return;
    if (base < nx) {
        float4 v = *(const float4*)(x + base);
        ushort4 o;
        o.x = f2b(v.x); o.y = f2b(v.y); o.z = f2b(v.z); o.w = f2b(v.w);
        *(ushort4*)(xb + base) = o;
    } else {
        ushort4 z = make_ushort4(0, 0, 0, 0);
        *(ushort4*)(xb + base) = z;   // pad row (index == N -> zeros)
        *(ushort4*)(hb + base) = z;
    }
}

// ---------------------------------------------------------------------------
// Kernel 2: pack weights into MFMA B-fragment order.
// wp00: per-k contiguous 16KB slices (k*8192 + (c*4+t)*512 + lane*8); cin
//       block c: first 4096 shorts = cin 0-63, second half cin 64-127.
// wpC : conv01 and conv11 k-slices interleaved: k*8192 + [0|4096] + ...
// ---------------------------------------------------------------------------
__global__ __launch_bounds__(256) void pack_kernel(
    const float* __restrict__ W00, const float* __restrict__ W01,
    const float* __restrict__ W10, const float* __restrict__ W11,
    const float* __restrict__ W12,
    unsigned short* __restrict__ wp00, unsigned short* __restrict__ wpC,
    unsigned short* __restrict__ wp10, unsigned short* __restrict__ wp12) {
    int g = blockIdx.x * blockDim.x + threadIdx.x;
    const float* W; int cinSteps; int which;
    if (g < 27648)      { W = W00; cinSteps = 4; which = 0; }
    else if (g < 41472) { g -= 27648; W = W01; cinSteps = 2; which = 1; }
    else if (g < 55296) { g -= 41472; W = W11; cinSteps = 2; which = 2; }
    else if (g < 56320) { g -= 55296; W = W10; cinSteps = 4; which = 3; }
    else if (g < 56832) { g -= 56320; W = W12; cinSteps = 2; which = 4; }
    else return;
    int lane = g & 63;
    int st   = g >> 6;
    int t    = st & 3;
    int s    = st >> 2;
    int q = lane >> 4, n16 = lane & 15;
    int k    = s / cinSteps;
    int cinb = (s % cinSteps) * 32;
    int Cin  = cinSteps * 32;
    int cout = t * 16 + n16;
    unsigned short o[8];
#pragma unroll
    for (int j = 0; j < 8; ++j) {
        float v = W[(size_t)(k * Cin + cinb + q * 8 + j) * 64 + cout];
        o[j] = f2b(v);
    }
    unsigned short* dst;
    if (which == 0)      dst = wp00 + (size_t)g * 8;
    else if (which == 1) dst = wpC + (size_t)k * 8192 +
                               ((size_t)(((s & 1) * 4 + t) * 64 + lane)) * 8;
    else if (which == 2) dst = wpC + (size_t)k * 8192 + 4096 +
                               ((size_t)(((s & 1) * 4 + t) * 64 + lane)) * 8;
    else if (which == 3) dst = wp10 + (size_t)g * 8;
    else                 dst = wp12 + (size_t)g * 8;
    *(ushort4*)(dst)     = make_ushort4(o[0], o[1], o[2], o[3]);
    *(ushort4*)(dst + 4) = make_ushort4(o[4], o[5], o[6], o[7]);
}

// ---------------------------------------------------------------------------
// Pass B: h0 = relu(sparse_conv(x, W00, b00)); h1 = relu(x @ W10 + b10)
// R3 structure (best-measured for passB): one block per 256-row strip
// (B-tile staging traffic is strip-size independent: 2x rows per block
// halves B L2 traffic).  64 rows/wave (4 rowsets).  Single phase with
// full-row 256B gathers (one contiguous burst per row per k).  B staged in
// LDS double-buffered with raw LDS-only barriers so gather prefetches stay
// in flight.  Gathers load DIRECTLY in MFMA A-layout.
// ---------------------------------------------------------------------------
__global__ __launch_bounds__(256, 2) void passB_kernel(
    const unsigned short* __restrict__ xb, const int* __restrict__ nbr,
    const unsigned short* __restrict__ wp00, const unsigned short* __restrict__ wp10,
    const float* __restrict__ b00, const float* __restrict__ b10,
    unsigned short* __restrict__ hb, int N) {
    __shared__ __align__(16) unsigned short bbuf[2][8192];
    __shared__ __align__(16) int lds_idx[256 * 27];
    const int tid  = threadIdx.x;
    const int lane = tid & 63;
    const int wv   = tid >> 6;
    const int q = lane >> 4, n16 = lane & 15;
    const int rowbase = blockIdx.x * 256 + wv * 64;

    // stage B(0) (issue first) and the strip's nbr slice
    int4 br[4];
#pragma unroll
    for (int j = 0; j < 4; ++j) br[j] = *(const int4*)(wp00 + j * 2048 + tid * 8);
    {
        long long gbase = (long long)blockIdx.x * 256 * 27;
        long long lim = (long long)N * 27 - 1;
        for (int i = tid; i < 6912; i += 256) {
            long long gi = gbase + i; if (gi > lim) gi = lim;
            lds_idx[i] = nbr[gi];
        }
    }
#pragma unroll
    for (int j = 0; j < 4; ++j) *(int4*)(&bbuf[0][j * 2048 + tid * 8]) = br[j];
    __syncthreads();

    f32x4 acc0[4][4];   // conv0_0 accum [rowset][t]
    f32x4 acc1[4][4];   // conv1_0 (1x1) accum
#pragma unroll
    for (int rs = 0; rs < 4; ++rs)
#pragma unroll
        for (int t = 0; t < 4; ++t) { acc0[rs][t] = (f32x4)0.f; acc1[rs][t] = (f32x4)0.f; }

    int idxb[4], own[4];
#pragma unroll
    for (int rs = 0; rs < 4; ++rs) {
        idxb[rs] = (wv * 64 + rs * 16 + n16) * 27;      // this lane's A-row
        own[rs]  = min(rowbase + rs * 16 + n16, N - 1); // own rows (clamped)
    }

    // gather D(0) in MFMA layout
    bf16x8 D[4][4];
#pragma unroll
    for (int rs = 0; rs < 4; ++rs) {
        const unsigned short* p = xb + (size_t)lds_idx[idxb[rs]] * 128 + q * 8;
#pragma unroll
        for (int s2 = 0; s2 < 4; ++s2) D[rs][s2] = *(const bf16x8*)(p + s2 * 32);
    }

    for (int k = 0; k < 27; ++k) {
        int buf = k & 1;
        if (k < 26) {   // B(k+1) global -> regs (issued BEFORE gathers)
            const unsigned short* src = wp00 + (size_t)(k + 1) * 8192;
#pragma unroll
            for (int j = 0; j < 4; ++j) br[j] = *(const int4*)(src + j * 2048 + tid * 8);
        }
        // next gather: idx(k+1) from LDS; past end -> own row (feeds 1x1)
        bf16x8 Dn[4][4];
#pragma unroll
        for (int rs = 0; rs < 4; ++rs) {
            int ian = (k + 1 < 27) ? lds_idx[idxb[rs] + k + 1] : own[rs];
            const unsigned short* p = xb + (size_t)ian * 128 + q * 8;
#pragma unroll
            for (int s2 = 0; s2 < 4; ++s2) Dn[rs][s2] = *(const bf16x8*)(p + s2 * 32);
        }
        // MFMA with LDS B(k); D(k) already in MFMA layout
        const unsigned short* lb = &bbuf[buf][0];
#pragma unroll
        for (int s2 = 0; s2 < 4; ++s2) {
#pragma unroll
            for (int t = 0; t < 4; ++t) {
                bf16x8 B = *(const bf16x8*)(lb + (s2 * 4 + t) * 512 + lane * 8);
#pragma unroll
                for (int rs = 0; rs < 4; ++rs)
                    acc0[rs][t] = MFMA(D[rs][s2], B, acc0[rs][t]);
            }
        }
        if (k < 26) {   // auto vmcnt here only drains B loads (older than gathers)
#pragma unroll
            for (int j = 0; j < 4; ++j)
                *(int4*)(&bbuf[buf ^ 1][j * 2048 + tid * 8]) = br[j];
        }
#pragma unroll
        for (int rs = 0; rs < 4; ++rs)
#pragma unroll
            for (int s2 = 0; s2 < 4; ++s2) D[rs][s2] = Dn[rs][s2];
        LDS_BARRIER();   // LDS-only drain: gathers stay in flight
    }

    // fused 1x1 conv: D now holds the wave's own rows (MFMA layout)
#pragma unroll
    for (int s2 = 0; s2 < 4; ++s2) {
#pragma unroll
        for (int t = 0; t < 4; ++t) {
            bf16x8 B = *(const bf16x8*)(wp10 + s2 * 2048 + t * 512 + lane * 8);
#pragma unroll
            for (int rs = 0; rs < 4; ++rs)
                acc1[rs][t] = MFMA(D[rs][s2], B, acc1[rs][t]);
        }
    }

    // epilogue: bias, relu, -> bf16, store h_comb.  C-layout: col=lane&15
#pragma unroll
    for (int rs = 0; rs < 4; ++rs)
#pragma unroll
        for (int t = 0; t < 4; ++t) {
            int col = t * 16 + n16;
            float bb0 = b00[col], bb1 = b10[col];
#pragma unroll
            for (int r = 0; r < 4; ++r) {
                int row = rowbase + rs * 16 + q * 4 + r;
                if (row < N) {
                    hb[(size_t)row * 128 + col]      = f2b(fmaxf(acc0[rs][t][r] + bb0, 0.f));
                    hb[(size_t)row * 128 + 64 + col] = f2b(fmaxf(acc1[rs][t][r] + bb1, 0.f));
                }
            }
        }
}

// ---------------------------------------------------------------------------
// Pass C: out0 = sparse_conv(h0, W01, b01);  t = relu(sparse_conv(h1, W11, b11));
//         out1 = t @ W12 + b12;  out = [out0 | out1] + x  (fp32)
// R5 structure (best-measured for passC): the two convs ARE the channel
// split — phase 1 gathers only h0 (bytes 0-127), phase 2 only h1 (bytes
// 128-255).  Per-phase gather working set 12.8MB -> better per-XCD L2 hit
// rate.  out0 stored at end of phase 1, freeing its accumulator.
// ---------------------------------------------------------------------------
__global__ __launch_bounds__(256, 3) void passC_kernel(
    const unsigned short* __restrict__ hb, const int* __restrict__ nbr,
    const float* __restrict__ x,
    const unsigned short* __restrict__ wpC, const unsigned short* __restrict__ wp12,
    const float* __restrict__ b01, const float* __restrict__ b11,
    const float* __restrict__ b12, float* __restrict__ out, int N) {
    __shared__ __align__(16) unsigned short bbuf[2][4096];
    __shared__ __align__(16) int lds_idx[128 * 27];
    const int tid  = threadIdx.x;
    const int lane = tid & 63;
    const int wv   = tid >> 6;
    const int q = lane >> 4, n16 = lane & 15;
    const int rowbase = blockIdx.x * 128 + wv * 32;

    int idxb[2];
#pragma unroll
    for (int rs = 0; rs < 2; ++rs) idxb[rs] = (wv * 32 + rs * 16 + n16) * 27;

    // ================= phase 1: conv01 on h0-half =================
    {
        int4 br[2];
#pragma unroll
        for (int j = 0; j < 2; ++j) br[j] = *(const int4*)(wpC + j * 2048 + tid * 8);
        {
            long long gbase = (long long)blockIdx.x * 128 * 27;
            long long lim = (long long)N * 27 - 1;
            for (int i = tid; i < 3456; i += 256) {
                long long gi = gbase + i; if (gi > lim) gi = lim;
                lds_idx[i] = nbr[gi];
            }
        }
#pragma unroll
        for (int j = 0; j < 2; ++j) *(int4*)(&bbuf[0][j * 2048 + tid * 8]) = br[j];
        __syncthreads();

        f32x4 accA[2][4];
#pragma unroll
        for (int rs = 0; rs < 2; ++rs)
#pragma unroll
            for (int t = 0; t < 4; ++t) accA[rs][t] = (f32x4)0.f;

        bf16x8 Da[2][2], Db[2][2], Dc[2][2];
#pragma unroll
        for (int rs = 0; rs < 2; ++rs) {
            const unsigned short* p0 = hb + (size_t)lds_idx[idxb[rs] + 0] * 128 + q * 8;
            Da[rs][0] = *(const bf16x8*)(p0);
            Da[rs][1] = *(const bf16x8*)(p0 + 32);
            const unsigned short* p1 = hb + (size_t)lds_idx[idxb[rs] + 1] * 128 + q * 8;
            Db[rs][0] = *(const bf16x8*)(p1);
            Db[rs][1] = *(const bf16x8*)(p1 + 32);
        }

        for (int k = 0; k < 27; ++k) {
            int buf = k & 1;
            if (k < 26) {
                const unsigned short* src = wpC + (size_t)(k + 1) * 8192;
#pragma unroll
                for (int j = 0; j < 2; ++j)
                    br[j] = *(const int4*)(src + j * 2048 + tid * 8);
            }
#pragma unroll
            for (int rs = 0; rs < 2; ++rs) {
                int j2 = min(k + 2, 26);   // clamp: harmless re-gather at tail
                const unsigned short* p =
                    hb + (size_t)lds_idx[idxb[rs] + j2] * 128 + q * 8;
                Dc[rs][0] = *(const bf16x8*)(p);
                Dc[rs][1] = *(const bf16x8*)(p + 32);
            }
            const unsigned short* lb = &bbuf[buf][0];
#pragma unroll
            for (int s2 = 0; s2 < 2; ++s2) {
#pragma unroll
                for (int t = 0; t < 4; ++t) {
                    bf16x8 B = *(const bf16x8*)(lb + (s2 * 4 + t) * 512 + lane * 8);
#pragma unroll
                    for (int rs = 0; rs < 2; ++rs)
                        accA[rs][t] = MFMA(Da[rs][s2], B, accA[rs][t]);
                }
            }
            if (k < 26) {
#pragma unroll
                for (int j = 0; j < 2; ++j)
                    *(int4*)(&bbuf[buf ^ 1][j * 2048 + tid * 8]) = br[j];
            }
#pragma unroll
            for (int rs = 0; rs < 2; ++rs)
#pragma unroll
                for (int s2 = 0; s2 < 2; ++s2) {
                    Da[rs][s2] = Db[rs][s2]; Db[rs][s2] = Dc[rs][s2];
                }
            LDS_BARRIER();
        }

        // epilogue 1: out0 = accA + b01 + x  (frees accA before phase 2)
#pragma unroll
        for (int rs = 0; rs < 2; ++rs)
#pragma unroll
            for (int t = 0; t < 4; ++t) {
                int col = t * 16 + n16;
                float bo = b01[col];
#pragma unroll
                for (int r = 0; r < 4; ++r) {
                    int row = rowbase + rs * 16 + q * 4 + r;
                    if (row < N) {
                        float xv = __builtin_nontemporal_load(x + (size_t)row * 128 + col);
                        __builtin_nontemporal_store(accA[rs][t][r] + bo + xv,
                                                    out + (size_t)row * 128 + col);
                    }
                }
            }
    }

    // ================= phase 2: conv11 on h1-half =================
    {
        int4 br[2];
#pragma unroll
        for (int j = 0; j < 2; ++j)
            br[j] = *(const int4*)(wpC + 4096 + j * 2048 + tid * 8);
#pragma unroll
        for (int j = 0; j < 2; ++j) *(int4*)(&bbuf[0][j * 2048 + tid * 8]) = br[j];
        __syncthreads();

        f32x4 accT[2][4];
#pragma unroll
        for (int rs = 0; rs < 2; ++rs)
#pragma unroll
            for (int t = 0; t < 4; ++t) accT[rs][t] = (f32x4)0.f;

        bf16x8 Da[2][2], Db[2][2], Dc[2][2];
#pragma unroll
        for (int rs = 0; rs < 2; ++rs) {
            const unsigned short* p0 =
                hb + (size_t)lds_idx[idxb[rs] + 0] * 128 + 64 + q * 8;
            Da[rs][0] = *(const bf16x8*)(p0);
            Da[rs][1] = *(const bf16x8*)(p0 + 32);
            const unsigned short* p1 =
                hb + (size_t)lds_idx[idxb[rs] + 1] * 128 + 64 + q * 8;
            Db[rs][0] = *(const bf16x8*)(p1);
            Db[rs][1] = *(const bf16x8*)(p1 + 32);
        }

        for (int k = 0; k < 27; ++k) {
            int buf = k & 1;
            if (k < 26) {
                const unsigned short* src = wpC + 4096 + (size_t)(k + 1) * 8192;
#pragma unroll
                for (int j = 0; j < 2; ++j)
                    br[j] = *(const int4*)(src + j * 2048 + tid * 8);
            }
#pragma unroll
            for (int rs = 0; rs < 2; ++rs) {
                int j2 = min(k + 2, 26);
                const unsigned short* p =
                    hb + (size_t)lds_idx[idxb[rs] + j2] * 128 + 64 + q * 8;
                Dc[rs][0] = *(const bf16x8*)(p);
                Dc[rs][1] = *(const bf16x8*)(p + 32);
            }
            const unsigned short* lb = &bbuf[buf][0];
#pragma unroll
            for (int s2 = 0; s2 < 2; ++s2) {
#pragma unroll
                for (int t = 0; t < 4; ++t) {
                    bf16x8 B = *(const bf16x8*)(lb + (s2 * 4 + t) * 512 + lane * 8);
#pragma unroll
                    for (int rs = 0; rs < 2; ++rs)
                        accT[rs][t] = MFMA(Da[rs][s2], B, accT[rs][t]);
                }
            }
            if (k < 26) {
#pragma unroll
                for (int j = 0; j < 2; ++j)
                    *(int4*)(&bbuf[buf ^ 1][j * 2048 + tid * 8]) = br[j];
            }
#pragma unroll
            for (int rs = 0; rs < 2; ++rs)
#pragma unroll
                for (int s2 = 0; s2 < 2; ++s2) {
                    Da[rs][s2] = Db[rs][s2]; Db[rs][s2] = Dc[rs][s2];
                }
            LDS_BARRIER();   // final one also fences lds_idx/bbuf for overlay
        }

        // t -> relu -> bf16 -> LDS scratch (per-wave private region).
        // Overlay: waves 0-2 use lds_idx (3 x 4608B = 13824B exactly),
        // wave 3 uses bbuf.  All idx/bbuf reads completed before the final
        // LDS_BARRIER above.
        unsigned short* myl = (wv < 3) ? ((unsigned short*)lds_idx + wv * 2304)
                                       : &bbuf[0][0];
#pragma unroll
        for (int rs = 0; rs < 2; ++rs)
#pragma unroll
            for (int t = 0; t < 4; ++t) {
                int col = t * 16 + n16;
                float bt = b11[col];
#pragma unroll
                for (int r = 0; r < 4; ++r) {
                    float tv = fmaxf(accT[rs][t][r] + bt, 0.f);
                    myl[(rs * 16 + q * 4 + r) * 72 + col] = f2b(tv);
                }
            }
        // per-wave private region: within-wave lgkm ordering suffices

        // mini-GEMM: out1 = relu(t) @ W12
        f32x4 accO1[2][4];
#pragma unroll
        for (int rs = 0; rs < 2; ++rs)
#pragma unroll
            for (int t = 0; t < 4; ++t) accO1[rs][t] = (f32x4)0.f;
#pragma unroll
        for (int s2 = 0; s2 < 2; ++s2) {
#pragma unroll
            for (int t = 0; t < 4; ++t) {
                bf16x8 B = *(const bf16x8*)(wp12 + s2 * 2048 + t * 512 + lane * 8);
#pragma unroll
                for (int rs = 0; rs < 2; ++rs) {
                    bf16x8 A = *(const bf16x8*)(myl + (rs * 16 + n16) * 72 + s2 * 32 + q * 8);
                    accO1[rs][t] = MFMA(A, B, accO1[rs][t]);
                }
            }
        }
#pragma unroll
        for (int rs = 0; rs < 2; ++rs)
#pragma unroll
            for (int t = 0; t < 4; ++t) {
                int col = t * 16 + n16;
                float bo = b12[col];
#pragma unroll
                for (int r = 0; r < 4; ++r) {
                    int row = rowbase + rs * 16 + q * 4 + r;
                    if (row < N) {
                        float xv = __builtin_nontemporal_load(x + (size_t)row * 128 + 64 + col);
                        __builtin_nontemporal_store(accO1[rs][t][r] + bo + xv,
                                                    out + (size_t)row * 128 + 64 + col);
                    }
                }
            }
    }
}

// ---------------------------------------------------------------------------
extern "C" void kernel_launch(void* const* d_in, const int* in_sizes, int n_in,
                              void* d_out, int out_size, void* d_ws, size_t ws_size,
                              hipStream_t stream) {
    const float* x   = (const float*)d_in[0];
    const int*   nbr = (const int*)d_in[1];
    const float* W00 = (const float*)d_in[2];
    const float* b00 = (const float*)d_in[3];
    const float* W01 = (const float*)d_in[4];
    const float* b01 = (const float*)d_in[5];
    const float* W10 = (const float*)d_in[6];
    const float* b10 = (const float*)d_in[7];
    const float* W11 = (const float*)d_in[8];
    const float* b11 = (const float*)d_in[9];
    const float* W12 = (const float*)d_in[10];
    const float* b12 = (const float*)d_in[11];
    float* out = (float*)d_out;
    int N = in_sizes[0] / 128;   // 100000

    // workspace carve-up
    char* ws = (char*)d_ws;
    size_t cur = 0;
    unsigned short* xb  = (unsigned short*)(ws + cur); cur += (size_t)(N + 1) * 128 * 2;
    unsigned short* hb  = (unsigned short*)(ws + cur); cur += (size_t)(N + 1) * 128 * 2;
    unsigned short* wp00 = (unsigned short*)(ws + cur); cur += 27648 * 8 * 2;
    unsigned short* wpC  = (unsigned short*)(ws + cur); cur += (size_t)27 * 8192 * 2;
    unsigned short* wp10 = (unsigned short*)(ws + cur); cur += 8192 * 2;
    unsigned short* wp12 = (unsigned short*)(ws + cur); cur += 4096 * 2;

    long long cvt_groups = ((long long)N * 128 + 128) / 4;
    int cvt_blocks = (int)((cvt_groups + 255) / 256);
    convert_kernel<<<cvt_blocks, 256, 0, stream>>>(x, xb, hb, N);
    pack_kernel<<<222, 256, 0, stream>>>(W00, W01, W10, W11, W12,
                                         wp00, wpC, wp10, wp12);
    int nstripsB = (N + 255) / 256;   // 391 strips of 256 rows
    passB_kernel<<<nstripsB, 256, 0, stream>>>(xb, nbr, wp00, wp10, b00, b10, hb, N);
    int nstripsC = (N + 127) / 128;   // 782 strips of 128 rows
    passC_kernel<<<nstripsC, 256, 0, stream>>>(hb, nbr, x, wpC, wp12,
                                               b01, b11, b12, out, N);
}

// Round 7
// 390.180 us; speedup vs baseline: 1.0708x; 1.0075x over previous
//
#include <hip/hip_runtime.h>
#include <hip/hip_bf16.h>
#include <stdint.h>

// MFMA fragment types (gfx950: mfma_f32_16x16x32_bf16 takes <8 x bf16>)
typedef __bf16 bf16x8 __attribute__((ext_vector_type(8)));
typedef float  f32x4  __attribute__((ext_vector_type(4)));

#define MFMA(A, B, C) __builtin_amdgcn_mfma_f32_16x16x32_bf16((A), (B), (C), 0, 0, 0)

// Raw workgroup barrier: waits LDS ops only, leaves global loads in flight
// (the compiler's __syncthreads() emits s_waitcnt vmcnt(0) which would drain
// our gather prefetch every k-iteration — that is the structural stall).
#define LDS_BARRIER() asm volatile("s_waitcnt lgkmcnt(0)\n\ts_barrier" ::: "memory")

// fp32 -> bf16 round-to-nearest-even
static __device__ __forceinline__ unsigned short f2b(float f) {
    union { float f; unsigned int u; } v; v.f = f;
    return (unsigned short)((v.u + 0x7FFFu + ((v.u >> 16) & 1u)) >> 16);
}

// ---------------------------------------------------------------------------
// Kernel 1 (fused prep): blocks [0, cvtBlocks) convert x fp32 -> bf16
// [N+1][128] (zero pad row N of x_bf16 and h_comb); blocks [cvtBlocks, +222)
// pack weights into MFMA B-fragment order.
// wp00: per-k 16KB slices (k*8192 + (s*4+t)*512 + lane*8); first 4096 shorts
//       of each slice = cin 0-63 (phase 0), second half cin 64-127 (phase 1).
// wpC : conv01 and conv11 k-slices interleaved: k*8192 + [0|4096] + ...
// ---------------------------------------------------------------------------
__global__ __launch_bounds__(256) void prep_kernel(
    const float* __restrict__ x, unsigned short* __restrict__ xb,
    unsigned short* __restrict__ hb, int N, int cvtBlocks,
    const float* __restrict__ W00, const float* __restrict__ W01,
    const float* __restrict__ W10, const float* __restrict__ W11,
    const float* __restrict__ W12,
    unsigned short* __restrict__ wp00, unsigned short* __restrict__ wpC,
    unsigned short* __restrict__ wp10, unsigned short* __restrict__ wp12) {
    if (blockIdx.x < (unsigned)cvtBlocks) {
        // ---- convert ----
        long long i = (long long)blockIdx.x * blockDim.x + threadIdx.x;
        long long base = i * 4;
        long long nx = (long long)N * 128;
        long long total = nx + 128;
        if (base >= total) return;
        if (base < nx) {
            float4 v = *(const float4*)(x + base);
            ushort4 o;
            o.x = f2b(v.x); o.y = f2b(v.y); o.z = f2b(v.z); o.w = f2b(v.w);
            *(ushort4*)(xb + base) = o;
        } else {
            ushort4 z = make_ushort4(0, 0, 0, 0);
            *(ushort4*)(xb + base) = z;   // pad row (index == N -> zeros)
            *(ushort4*)(hb + base) = z;
        }
        return;
    }
    // ---- pack ----
    int g = (blockIdx.x - cvtBlocks) * blockDim.x + threadIdx.x;
    const float* W; int cinSteps; int which;
    if (g < 27648)      { W = W00; cinSteps = 4; which = 0; }
    else if (g < 41472) { g -= 27648; W = W01; cinSteps = 2; which = 1; }
    else if (g < 55296) { g -= 41472; W = W11; cinSteps = 2; which = 2; }
    else if (g < 56320) { g -= 55296; W = W10; cinSteps = 4; which = 3; }
    else if (g < 56832) { g -= 56320; W = W12; cinSteps = 2; which = 4; }
    else return;
    int lane = g & 63;
    int st   = g >> 6;
    int t    = st & 3;
    int s    = st >> 2;
    int q = lane >> 4, n16 = lane & 15;
    int k    = s / cinSteps;
    int cinb = (s % cinSteps) * 32;
    int Cin  = cinSteps * 32;
    int cout = t * 16 + n16;
    unsigned short o[8];
#pragma unroll
    for (int j = 0; j < 8; ++j) {
        float v = W[(size_t)(k * Cin + cinb + q * 8 + j) * 64 + cout];
        o[j] = f2b(v);
    }
    unsigned short* dst;
    if (which == 0)      dst = wp00 + (size_t)g * 8;
    else if (which == 1) dst = wpC + (size_t)k * 8192 +
                               ((size_t)(((s & 1) * 4 + t) * 64 + lane)) * 8;
    else if (which == 2) dst = wpC + (size_t)k * 8192 + 4096 +
                               ((size_t)(((s & 1) * 4 + t) * 64 + lane)) * 8;
    else if (which == 3) dst = wp10 + (size_t)g * 8;
    else                 dst = wp12 + (size_t)g * 8;
    *(ushort4*)(dst)     = make_ushort4(o[0], o[1], o[2], o[3]);
    *(ushort4*)(dst + 4) = make_ushort4(o[4], o[5], o[6], o[7]);
}

// ---------------------------------------------------------------------------
// Pass B: h0 = relu(sparse_conv(x, W00, b00)); h1 = relu(x @ W10 + b10)
// 256-row strips (R3's best B-staging geometry) + CHANNEL-SPLIT phases
// (R5's passC mechanism, now isolated at the proven strip size): phase 0
// gathers only cin 0-63 (one 128B line per row), phase 1 cin 64-127.
// Per-phase gather working set 12.8MB (vs 25.6) -> better per-XCD L2 hit
// rate at identical total bytes and line count.  Accumulators persist in
// AGPRs across phases.  64 rows/wave (4 rowsets), 1-deep gather prefetch in
// MFMA A-layout; B half-tiles (8KB) staged in LDS double-buffered with
// LDS-only barriers so gathers stay in flight.
// ---------------------------------------------------------------------------
__global__ __launch_bounds__(256, 2) void passB_kernel(
    const unsigned short* __restrict__ xb, const int* __restrict__ nbr,
    const unsigned short* __restrict__ wp00, const unsigned short* __restrict__ wp10,
    const float* __restrict__ b00, const float* __restrict__ b10,
    unsigned short* __restrict__ hb, int N) {
    __shared__ __align__(16) unsigned short bbuf[2][4096];
    __shared__ __align__(16) int lds_idx[256 * 27];
    const int tid  = threadIdx.x;
    const int lane = tid & 63;
    const int wv   = tid >> 6;
    const int q = lane >> 4, n16 = lane & 15;
    const int rowbase = blockIdx.x * 256 + wv * 64;

    f32x4 acc0[4][4];   // conv0_0 accum [rowset][t] — spans both phases
    f32x4 acc1[4][4];   // conv1_0 (1x1) accum — spans both phases
#pragma unroll
    for (int rs = 0; rs < 4; ++rs)
#pragma unroll
        for (int t = 0; t < 4; ++t) { acc0[rs][t] = (f32x4)0.f; acc1[rs][t] = (f32x4)0.f; }

    int idxb[4], own[4];
#pragma unroll
    for (int rs = 0; rs < 4; ++rs) {
        idxb[rs] = (wv * 64 + rs * 16 + n16) * 27;      // this lane's A-row
        own[rs]  = min(rowbase + rs * 16 + n16, N - 1); // own rows (clamped)
    }

#pragma unroll
    for (int ph = 0; ph < 2; ++ph) {
        const int choff = ph * 64;   // channel offset in shorts (one 128B line)
        // stage B(0) half-tile for this phase
        int4 br[2];
#pragma unroll
        for (int j = 0; j < 2; ++j)
            br[j] = *(const int4*)(wp00 + ph * 4096 + j * 2048 + tid * 8);
        if (ph == 0) {  // stage the strip's nbr slice once
            long long gbase = (long long)blockIdx.x * 256 * 27;
            long long lim = (long long)N * 27 - 1;
            for (int i = tid; i < 6912; i += 256) {
                long long gi = gbase + i; if (gi > lim) gi = lim;
                lds_idx[i] = nbr[gi];
            }
        }
#pragma unroll
        for (int j = 0; j < 2; ++j) *(int4*)(&bbuf[0][j * 2048 + tid * 8]) = br[j];
        __syncthreads();   // phase boundary: full drain (2x per kernel, cheap)

        // gather D(0) in MFMA layout (this phase's 128B line of each row)
        bf16x8 D[4][2], Dn[4][2];
#pragma unroll
        for (int rs = 0; rs < 4; ++rs) {
            const unsigned short* p =
                xb + (size_t)lds_idx[idxb[rs]] * 128 + choff + q * 8;
            D[rs][0] = *(const bf16x8*)(p);
            D[rs][1] = *(const bf16x8*)(p + 32);
        }

        for (int k = 0; k < 27; ++k) {
            int buf = k & 1;
            if (k < 26) {   // B(k+1) half-tile -> regs (issued BEFORE gathers)
                const unsigned short* src = wp00 + ph * 4096 + (size_t)(k + 1) * 8192;
#pragma unroll
                for (int j = 0; j < 2; ++j)
                    br[j] = *(const int4*)(src + j * 2048 + tid * 8);
            }
            // next gather: idx(k+1) from LDS; past end -> own row (feeds 1x1)
#pragma unroll
            for (int rs = 0; rs < 4; ++rs) {
                int ian = (k + 1 < 27) ? lds_idx[idxb[rs] + k + 1] : own[rs];
                const unsigned short* p = xb + (size_t)ian * 128 + choff + q * 8;
                Dn[rs][0] = *(const bf16x8*)(p);
                Dn[rs][1] = *(const bf16x8*)(p + 32);
            }
            // MFMA with LDS B(k); D(k) already in MFMA layout
            const unsigned short* lb = &bbuf[buf][0];
#pragma unroll
            for (int s2 = 0; s2 < 2; ++s2) {
#pragma unroll
                for (int t = 0; t < 4; ++t) {
                    bf16x8 B = *(const bf16x8*)(lb + (s2 * 4 + t) * 512 + lane * 8);
#pragma unroll
                    for (int rs = 0; rs < 4; ++rs)
                        acc0[rs][t] = MFMA(D[rs][s2], B, acc0[rs][t]);
                }
            }
            if (k < 26) {   // auto vmcnt here only drains B loads (older than gathers)
#pragma unroll
                for (int j = 0; j < 2; ++j)
                    *(int4*)(&bbuf[buf ^ 1][j * 2048 + tid * 8]) = br[j];
            }
#pragma unroll
            for (int rs = 0; rs < 4; ++rs)
#pragma unroll
                for (int s2 = 0; s2 < 2; ++s2) D[rs][s2] = Dn[rs][s2];
            LDS_BARRIER();   // LDS-only drain: gathers stay in flight
        }

        // fused 1x1 conv, this phase's cin half: D = own rows
#pragma unroll
        for (int s2 = 0; s2 < 2; ++s2) {
#pragma unroll
            for (int t = 0; t < 4; ++t) {
                bf16x8 B = *(const bf16x8*)(wp10 + ((ph * 2 + s2) * 4 + t) * 512 + lane * 8);
#pragma unroll
                for (int rs = 0; rs < 4; ++rs)
                    acc1[rs][t] = MFMA(D[rs][s2], B, acc1[rs][t]);
            }
        }
    }

    // epilogue: bias, relu, -> bf16, store h_comb.  C-layout: col=lane&15
#pragma unroll
    for (int rs = 0; rs < 4; ++rs)
#pragma unroll
        for (int t = 0; t < 4; ++t) {
            int col = t * 16 + n16;
            float bb0 = b00[col], bb1 = b10[col];
#pragma unroll
            for (int r = 0; r < 4; ++r) {
                int row = rowbase + rs * 16 + q * 4 + r;
                if (row < N) {
                    hb[(size_t)row * 128 + col]      = f2b(fmaxf(acc0[rs][t][r] + bb0, 0.f));
                    hb[(size_t)row * 128 + 64 + col] = f2b(fmaxf(acc1[rs][t][r] + bb1, 0.f));
                }
            }
        }
}

// ---------------------------------------------------------------------------
// Pass C: out0 = sparse_conv(h0, W01, b01);  t = relu(sparse_conv(h1, W11, b11));
//         out1 = t @ W12 + b12;  out = [out0 | out1] + x  (fp32)
// R5/R6 structure (best-measured): the two convs ARE the channel split —
// phase 1 gathers only h0 (bytes 0-127), phase 2 only h1 (bytes 128-255).
// ---------------------------------------------------------------------------
__global__ __launch_bounds__(256, 3) void passC_kernel(
    const unsigned short* __restrict__ hb, const int* __restrict__ nbr,
    const float* __restrict__ x,
    const unsigned short* __restrict__ wpC, const unsigned short* __restrict__ wp12,
    const float* __restrict__ b01, const float* __restrict__ b11,
    const float* __restrict__ b12, float* __restrict__ out, int N) {
    __shared__ __align__(16) unsigned short bbuf[2][4096];
    __shared__ __align__(16) int lds_idx[128 * 27];
    const int tid  = threadIdx.x;
    const int lane = tid & 63;
    const int wv   = tid >> 6;
    const int q = lane >> 4, n16 = lane & 15;
    const int rowbase = blockIdx.x * 128 + wv * 32;

    int idxb[2];
#pragma unroll
    for (int rs = 0; rs < 2; ++rs) idxb[rs] = (wv * 32 + rs * 16 + n16) * 27;

    // ================= phase 1: conv01 on h0-half =================
    {
        int4 br[2];
#pragma unroll
        for (int j = 0; j < 2; ++j) br[j] = *(const int4*)(wpC + j * 2048 + tid * 8);
        {
            long long gbase = (long long)blockIdx.x * 128 * 27;
            long long lim = (long long)N * 27 - 1;
            for (int i = tid; i < 3456; i += 256) {
                long long gi = gbase + i; if (gi > lim) gi = lim;
                lds_idx[i] = nbr[gi];
            }
        }
#pragma unroll
        for (int j = 0; j < 2; ++j) *(int4*)(&bbuf[0][j * 2048 + tid * 8]) = br[j];
        __syncthreads();

        f32x4 accA[2][4];
#pragma unroll
        for (int rs = 0; rs < 2; ++rs)
#pragma unroll
            for (int t = 0; t < 4; ++t) accA[rs][t] = (f32x4)0.f;

        bf16x8 Da[2][2], Db[2][2], Dc[2][2];
#pragma unroll
        for (int rs = 0; rs < 2; ++rs) {
            const unsigned short* p0 = hb + (size_t)lds_idx[idxb[rs] + 0] * 128 + q * 8;
            Da[rs][0] = *(const bf16x8*)(p0);
            Da[rs][1] = *(const bf16x8*)(p0 + 32);
            const unsigned short* p1 = hb + (size_t)lds_idx[idxb[rs] + 1] * 128 + q * 8;
            Db[rs][0] = *(const bf16x8*)(p1);
            Db[rs][1] = *(const bf16x8*)(p1 + 32);
        }

        for (int k = 0; k < 27; ++k) {
            int buf = k & 1;
            if (k < 26) {
                const unsigned short* src = wpC + (size_t)(k + 1) * 8192;
#pragma unroll
                for (int j = 0; j < 2; ++j)
                    br[j] = *(const int4*)(src + j * 2048 + tid * 8);
            }
#pragma unroll
            for (int rs = 0; rs < 2; ++rs) {
                int j2 = min(k + 2, 26);   // clamp: harmless re-gather at tail
                const unsigned short* p =
                    hb + (size_t)lds_idx[idxb[rs] + j2] * 128 + q * 8;
                Dc[rs][0] = *(const bf16x8*)(p);
                Dc[rs][1] = *(const bf16x8*)(p + 32);
            }
            const unsigned short* lb = &bbuf[buf][0];
#pragma unroll
            for (int s2 = 0; s2 < 2; ++s2) {
#pragma unroll
                for (int t = 0; t < 4; ++t) {
                    bf16x8 B = *(const bf16x8*)(lb + (s2 * 4 + t) * 512 + lane * 8);
#pragma unroll
                    for (int rs = 0; rs < 2; ++rs)
                        accA[rs][t] = MFMA(Da[rs][s2], B, accA[rs][t]);
                }
            }
            if (k < 26) {
#pragma unroll
                for (int j = 0; j < 2; ++j)
                    *(int4*)(&bbuf[buf ^ 1][j * 2048 + tid * 8]) = br[j];
            }
#pragma unroll
            for (int rs = 0; rs < 2; ++rs)
#pragma unroll
                for (int s2 = 0; s2 < 2; ++s2) {
                    Da[rs][s2] = Db[rs][s2]; Db[rs][s2] = Dc[rs][s2];
                }
            LDS_BARRIER();
        }

        // epilogue 1: out0 = accA + b01 + x  (frees accA before phase 2)
#pragma unroll
        for (int rs = 0; rs < 2; ++rs)
#pragma unroll
            for (int t = 0; t < 4; ++t) {
                int col = t * 16 + n16;
                float bo = b01[col];
#pragma unroll
                for (int r = 0; r < 4; ++r) {
                    int row = rowbase + rs * 16 + q * 4 + r;
                    if (row < N) {
                        float xv = __builtin_nontemporal_load(x + (size_t)row * 128 + col);
                        __builtin_nontemporal_store(accA[rs][t][r] + bo + xv,
                                                    out + (size_t)row * 128 + col);
                    }
                }
            }
    }

    // ================= phase 2: conv11 on h1-half =================
    {
        int4 br[2];
#pragma unroll
        for (int j = 0; j < 2; ++j)
            br[j] = *(const int4*)(wpC + 4096 + j * 2048 + tid * 8);
#pragma unroll
        for (int j = 0; j < 2; ++j) *(int4*)(&bbuf[0][j * 2048 + tid * 8]) = br[j];
        __syncthreads();

        f32x4 accT[2][4];
#pragma unroll
        for (int rs = 0; rs < 2; ++rs)
#pragma unroll
            for (int t = 0; t < 4; ++t) accT[rs][t] = (f32x4)0.f;

        bf16x8 Da[2][2], Db[2][2], Dc[2][2];
#pragma unroll
        for (int rs = 0; rs < 2; ++rs) {
            const unsigned short* p0 =
                hb + (size_t)lds_idx[idxb[rs] + 0] * 128 + 64 + q * 8;
            Da[rs][0] = *(const bf16x8*)(p0);
            Da[rs][1] = *(const bf16x8*)(p0 + 32);
            const unsigned short* p1 =
                hb + (size_t)lds_idx[idxb[rs] + 1] * 128 + 64 + q * 8;
            Db[rs][0] = *(const bf16x8*)(p1);
            Db[rs][1] = *(const bf16x8*)(p1 + 32);
        }

        for (int k = 0; k < 27; ++k) {
            int buf = k & 1;
            if (k < 26) {
                const unsigned short* src = wpC + 4096 + (size_t)(k + 1) * 8192;
#pragma unroll
                for (int j = 0; j < 2; ++j)
                    br[j] = *(const int4*)(src + j * 2048 + tid * 8);
            }
#pragma unroll
            for (int rs = 0; rs < 2; ++rs) {
                int j2 = min(k + 2, 26);
                const unsigned short* p =
                    hb + (size_t)lds_idx[idxb[rs] + j2] * 128 + 64 + q * 8;
                Dc[rs][0] = *(const bf16x8*)(p);
                Dc[rs][1] = *(const bf16x8*)(p + 32);
            }
            const unsigned short* lb = &bbuf[buf][0];
#pragma unroll
            for (int s2 = 0; s2 < 2; ++s2) {
#pragma unroll
                for (int t = 0; t < 4; ++t) {
                    bf16x8 B = *(const bf16x8*)(lb + (s2 * 4 + t) * 512 + lane * 8);
#pragma unroll
                    for (int rs = 0; rs < 2; ++rs)
                        accT[rs][t] = MFMA(Da[rs][s2], B, accT[rs][t]);
                }
            }
            if (k < 26) {
#pragma unroll
                for (int j = 0; j < 2; ++j)
                    *(int4*)(&bbuf[buf ^ 1][j * 2048 + tid * 8]) = br[j];
            }
#pragma unroll
            for (int rs = 0; rs < 2; ++rs)
#pragma unroll
                for (int s2 = 0; s2 < 2; ++s2) {
                    Da[rs][s2] = Db[rs][s2]; Db[rs][s2] = Dc[rs][s2];
                }
            LDS_BARRIER();   // final one also fences lds_idx/bbuf for overlay
        }

        // t -> relu -> bf16 -> LDS scratch (per-wave private region).
        // Overlay: waves 0-2 use lds_idx (3 x 4608B = 13824B exactly),
        // wave 3 uses bbuf.  All idx/bbuf reads completed before the final
        // LDS_BARRIER above.
        unsigned short* myl = (wv < 3) ? ((unsigned short*)lds_idx + wv * 2304)
                                       : &bbuf[0][0];
#pragma unroll
        for (int rs = 0; rs < 2; ++rs)
#pragma unroll
            for (int t = 0; t < 4; ++t) {
                int col = t * 16 + n16;
                float bt = b11[col];
#pragma unroll
                for (int r = 0; r < 4; ++r) {
                    float tv = fmaxf(accT[rs][t][r] + bt, 0.f);
                    myl[(rs * 16 + q * 4 + r) * 72 + col] = f2b(tv);
                }
            }
        // per-wave private region: within-wave lgkm ordering suffices

        // mini-GEMM: out1 = relu(t) @ W12
        f32x4 accO1[2][4];
#pragma unroll
        for (int rs = 0; rs < 2; ++rs)
#pragma unroll
            for (int t = 0; t < 4; ++t) accO1[rs][t] = (f32x4)0.f;
#pragma unroll
        for (int s2 = 0; s2 < 2; ++s2) {
#pragma unroll
            for (int t = 0; t < 4; ++t) {
                bf16x8 B = *(const bf16x8*)(wp12 + s2 * 2048 + t * 512 + lane * 8);
#pragma unroll
                for (int rs = 0; rs < 2; ++rs) {
                    bf16x8 A = *(const bf16x8*)(myl + (rs * 16 + n16) * 72 + s2 * 32 + q * 8);
                    accO1[rs][t] = MFMA(A, B, accO1[rs][t]);
                }
            }
        }
#pragma unroll
        for (int rs = 0; rs < 2; ++rs)
#pragma unroll
            for (int t = 0; t < 4; ++t) {
                int col = t * 16 + n16;
                float bo = b12[col];
#pragma unroll
                for (int r = 0; r < 4; ++r) {
                    int row = rowbase + rs * 16 + q * 4 + r;
                    if (row < N) {
                        float xv = __builtin_nontemporal_load(x + (size_t)row * 128 + 64 + col);
                        __builtin_nontemporal_store(accO1[rs][t][r] + bo + xv,
                                                    out + (size_t)row * 128 + 64 + col);
                    }
                }
            }
    }
}

// ---------------------------------------------------------------------------
extern "C" void kernel_launch(void* const* d_in, const int* in_sizes, int n_in,
                              void* d_out, int out_size, void* d_ws, size_t ws_size,
                              hipStream_t stream) {
    const float* x   = (const float*)d_in[0];
    const int*   nbr = (const int*)d_in[1];
    const float* W00 = (const float*)d_in[2];
    const float* b00 = (const float*)d_in[3];
    const float* W01 = (const float*)d_in[4];
    const float* b01 = (const float*)d_in[5];
    const float* W10 = (const float*)d_in[6];
    const float* b10 = (const float*)d_in[7];
    const float* W11 = (const float*)d_in[8];
    const float* b11 = (const float*)d_in[9];
    const float* W12 = (const float*)d_in[10];
    const float* b12 = (const float*)d_in[11];
    float* out = (float*)d_out;
    int N = in_sizes[0] / 128;   // 100000

    // workspace carve-up
    char* ws = (char*)d_ws;
    size_t cur = 0;
    unsigned short* xb  = (unsigned short*)(ws + cur); cur += (size_t)(N + 1) * 128 * 2;
    unsigned short* hb  = (unsigned short*)(ws + cur); cur += (size_t)(N + 1) * 128 * 2;
    unsigned short* wp00 = (unsigned short*)(ws + cur); cur += 27648 * 8 * 2;
    unsigned short* wpC  = (unsigned short*)(ws + cur); cur += (size_t)27 * 8192 * 2;
    unsigned short* wp10 = (unsigned short*)(ws + cur); cur += 8192 * 2;
    unsigned short* wp12 = (unsigned short*)(ws + cur); cur += 4096 * 2;

    long long cvt_groups = ((long long)N * 128 + 128) / 4;
    int cvt_blocks = (int)((cvt_groups + 255) / 256);
    prep_kernel<<<cvt_blocks + 222, 256, 0, stream>>>(
        x, xb, hb, N, cvt_blocks,
        W00, W01, W10, W11, W12, wp00, wpC, wp10, wp12);
    int nstripsB = (N + 255) / 256;   // 391 strips of 256 rows
    passB_kernel<<<nstripsB, 256, 0, stream>>>(xb, nbr, wp00, wp10, b00, b10, hb, N);
    int nstripsC = (N + 127) / 128;   // 782 strips of 128 rows
    passC_kernel<<<nstripsC, 256, 0, stream>>>(hb, nbr, x, wpC, wp12,
                                               b01, b11, b12, out, N);
}